// Round 1
// baseline (1386.442 us; speedup 1.0000x reference)
//
#include <hip/hip_runtime.h>
#include <math.h>

#define LN_EPS 1e-5f

__device__ __forceinline__ float silu_f(float x) {
    return x / (1.0f + __expf(-x));
}

// Block-wide reduction of (sum, sumsq). blockDim.x == 256 (4 waves of 64).
__device__ __forceinline__ float2 block_reduce2(float2 p, float2* sbuf) {
    #pragma unroll
    for (int off = 32; off > 0; off >>= 1) {
        p.x += __shfl_down(p.x, off, 64);
        p.y += __shfl_down(p.y, off, 64);
    }
    int lane = threadIdx.x & 63;
    int wid  = threadIdx.x >> 6;
    if (lane == 0) sbuf[wid] = p;
    __syncthreads();
    if (threadIdx.x == 0) {
        float2 r = sbuf[0];
        for (int i = 1; i < 4; ++i) { r.x += sbuf[i].x; r.y += sbuf[i].y; }
        sbuf[0] = r;
    }
    __syncthreads();
    return sbuf[0];
}

// ---------------------------------------------------------------------------
// LN (no affine) + SiLU, one block per row of 1024. 256 thr * 1 float4 each.
// ---------------------------------------------------------------------------
__global__ __launch_bounds__(256) void ln_silu_kernel(
    const float* __restrict__ x, float* __restrict__ out, int C)
{
    __shared__ float2 sbuf[4];
    int row = blockIdx.x;
    const float4* xr = (const float4*)(x + (size_t)row * C);
    float4 v = xr[threadIdx.x];
    float2 p;
    p.x = v.x + v.y + v.z + v.w;
    p.y = v.x*v.x + v.y*v.y + v.z*v.z + v.w*v.w;
    float2 s = block_reduce2(p, sbuf);
    float mean = s.x / (float)C;
    float var  = s.y / (float)C - mean * mean;
    float rstd = rsqrtf(var + LN_EPS);
    float4 y;
    y.x = silu_f((v.x - mean) * rstd);
    y.y = silu_f((v.y - mean) * rstd);
    y.z = silu_f((v.z - mean) * rstd);
    y.w = silu_f((v.w - mean) * rstd);
    ((float4*)(out + (size_t)row * C))[threadIdx.x] = y;
}

// ---------------------------------------------------------------------------
// Affine LN in place, then multiply by scale. One block per row of 1024.
// ---------------------------------------------------------------------------
__global__ __launch_bounds__(256) void ln_affine_kernel(
    float* __restrict__ q, const float* __restrict__ g,
    const float* __restrict__ be, float scale, int C)
{
    __shared__ float2 sbuf[4];
    int row = blockIdx.x;
    float4* qr = (float4*)(q + (size_t)row * C);
    float4 v = qr[threadIdx.x];
    float2 p;
    p.x = v.x + v.y + v.z + v.w;
    p.y = v.x*v.x + v.y*v.y + v.z*v.z + v.w*v.w;
    float2 s = block_reduce2(p, sbuf);
    float mean = s.x / (float)C;
    float var  = s.y / (float)C - mean * mean;
    float rstd = rsqrtf(var + LN_EPS);
    float4 gv = ((const float4*)g)[threadIdx.x];
    float4 bv = ((const float4*)be)[threadIdx.x];
    float4 y;
    y.x = ((v.x - mean) * rstd * gv.x + bv.x) * scale;
    y.y = ((v.y - mean) * rstd * gv.y + bv.y) * scale;
    y.z = ((v.z - mean) * rstd * gv.z + bv.z) * scale;
    y.w = ((v.w - mean) * rstd * gv.w + bv.w) * scale;
    qr[threadIdx.x] = y;
}

// ---------------------------------------------------------------------------
// C[M,Nn] = op(A)[M,K] @ W[K,Nn] + bias.  op = SiLU if SILU_A.
// 64x64 tile, K-tile 16, 256 threads, 4x4 micro-tile per thread.
// ---------------------------------------------------------------------------
template<bool SILU_A>
__global__ __launch_bounds__(256) void gemm_bias_kernel(
    const float* __restrict__ A, const float* __restrict__ W,
    const float* __restrict__ bias, float* __restrict__ Cc,
    int M, int Nn, int K)
{
    __shared__ float As[16][68];   // [k][row], pad 68 keeps float4 alignment + 2-way-max conflicts
    __shared__ float Bs[16][64];   // [k][col]
    int bx = blockIdx.x, by = blockIdx.y;
    int t  = threadIdx.x;
    int tx = t & 15, ty = t >> 4;   // 16x16 compute grid
    int ar = t >> 2;                // 0..63 A-row within tile
    int ak = (t & 3) * 4;           // 0,4,8,12 A k-offset
    int bk = t >> 4;                // 0..15 B k-row
    int bc = (t & 15) * 4;          // B col offset

    float acc[4][4] = {{0.f}};
    const float* Arow = A + (size_t)(by * 64 + ar) * K;

    for (int kt = 0; kt < K; kt += 16) {
        float4 av = *(const float4*)(Arow + kt + ak);
        if (SILU_A) {
            av.x = silu_f(av.x); av.y = silu_f(av.y);
            av.z = silu_f(av.z); av.w = silu_f(av.w);
        }
        float4 bv = *(const float4*)(W + (size_t)(kt + bk) * Nn + bx * 64 + bc);
        As[ak + 0][ar] = av.x;
        As[ak + 1][ar] = av.y;
        As[ak + 2][ar] = av.z;
        As[ak + 3][ar] = av.w;
        *(float4*)(&Bs[bk][bc]) = bv;
        __syncthreads();
        #pragma unroll
        for (int kk = 0; kk < 16; ++kk) {
            float a0 = As[kk][ty*4+0], a1 = As[kk][ty*4+1];
            float a2 = As[kk][ty*4+2], a3 = As[kk][ty*4+3];
            float b0 = Bs[kk][tx*4+0], b1 = Bs[kk][tx*4+1];
            float b2 = Bs[kk][tx*4+2], b3 = Bs[kk][tx*4+3];
            acc[0][0] += a0*b0; acc[0][1] += a0*b1; acc[0][2] += a0*b2; acc[0][3] += a0*b3;
            acc[1][0] += a1*b0; acc[1][1] += a1*b1; acc[1][2] += a1*b2; acc[1][3] += a1*b3;
            acc[2][0] += a2*b0; acc[2][1] += a2*b1; acc[2][2] += a2*b2; acc[2][3] += a2*b3;
            acc[3][0] += a3*b0; acc[3][1] += a3*b1; acc[3][2] += a3*b2; acc[3][3] += a3*b3;
        }
        __syncthreads();
    }

    int col0 = bx * 64 + tx * 4;
    float4 bb = *(const float4*)(bias + col0);
    #pragma unroll
    for (int i = 0; i < 4; ++i) {
        int row = by * 64 + ty * 4 + i;
        float4 ov;
        ov.x = acc[i][0] + bb.x;
        ov.y = acc[i][1] + bb.y;
        ov.z = acc[i][2] + bb.z;
        ov.w = acc[i][3] + bb.w;
        *(float4*)(Cc + (size_t)row * Nn + col0) = ov;
    }
}

// ---------------------------------------------------------------------------
// Flash attention (fp32, online softmax).
// Block: 256 threads = 64 query rows x 4 col-groups, one (b, h, 64-row tile).
// Iterates 16-key tiles. q is already scaled by inner^-0.5.
// ---------------------------------------------------------------------------
__global__ __launch_bounds__(256) void flash_kernel(
    const float* __restrict__ q, const float* __restrict__ k,
    const float* __restrict__ v, float* __restrict__ o,
    int N, int HD)
{
    __shared__ float Qs[64][68];
    __shared__ float Ks[16][68];
    __shared__ float Vs[16][68];
    __shared__ float Ps[64][17];

    int qt = blockIdx.x, h = blockIdx.y, b = blockIdx.z;
    int t  = threadIdx.x;
    int r  = t >> 2;     // query row in tile
    int cg = t & 3;      // col group (16 dims each)
    int d0 = cg * 16;

    size_t base = (size_t)b * N * HD + (size_t)h * 64;

    // Load 64x64 Q tile: each thread 4 float4s of its row r.
    {
        const float* qp = q + base + (size_t)(qt * 64 + r) * HD + d0;
        #pragma unroll
        for (int i = 0; i < 4; ++i) {
            float4 tv = *(const float4*)(qp + i * 4);
            Qs[r][d0 + i*4 + 0] = tv.x;
            Qs[r][d0 + i*4 + 1] = tv.y;
            Qs[r][d0 + i*4 + 2] = tv.z;
            Qs[r][d0 + i*4 + 3] = tv.w;
        }
    }

    float m = -INFINITY, l = 0.f;
    float oacc[16];
    #pragma unroll
    for (int i = 0; i < 16; ++i) oacc[i] = 0.f;

    int kr = t >> 4;          // 0..15 for K/V loads
    int kc = (t & 15) * 4;

    for (int kt = 0; kt < N; kt += 16) {
        __syncthreads();      // previous iteration's reads of Ks/Vs done
        {
            const float* kp = k + base + (size_t)(kt + kr) * HD + kc;
            const float* vp = v + base + (size_t)(kt + kr) * HD + kc;
            float4 kv = *(const float4*)kp;
            float4 vv = *(const float4*)vp;
            *(float4*)(&Ks[kr][kc]) = kv;
            *(float4*)(&Vs[kr][kc]) = vv;
        }
        __syncthreads();

        // scores: 4 keys per thread, 64-dim dots from LDS
        float s0 = 0.f, s1 = 0.f, s2 = 0.f, s3 = 0.f;
        int j0 = cg * 4;
        #pragma unroll
        for (int d = 0; d < 64; ++d) {
            float qv = Qs[r][d];
            s0 += qv * Ks[j0 + 0][d];
            s1 += qv * Ks[j0 + 1][d];
            s2 += qv * Ks[j0 + 2][d];
            s3 += qv * Ks[j0 + 3][d];
        }

        // online softmax over this row's 16 new scores
        float mt = fmaxf(fmaxf(s0, s1), fmaxf(s2, s3));
        mt = fmaxf(mt, __shfl_xor(mt, 1, 64));
        mt = fmaxf(mt, __shfl_xor(mt, 2, 64));
        float mnew = fmaxf(m, mt);
        float alpha = __expf(m - mnew);
        float p0 = __expf(s0 - mnew);
        float p1 = __expf(s1 - mnew);
        float p2 = __expf(s2 - mnew);
        float p3 = __expf(s3 - mnew);
        float psum = p0 + p1 + p2 + p3;
        psum += __shfl_xor(psum, 1, 64);
        psum += __shfl_xor(psum, 2, 64);
        l = l * alpha + psum;
        m = mnew;
        #pragma unroll
        for (int i = 0; i < 16; ++i) oacc[i] *= alpha;

        Ps[r][j0 + 0] = p0;
        Ps[r][j0 + 1] = p1;
        Ps[r][j0 + 2] = p2;
        Ps[r][j0 + 3] = p3;
        __syncthreads();

        #pragma unroll
        for (int j = 0; j < 16; ++j) {
            float p = Ps[r][j];
            #pragma unroll
            for (int dd = 0; dd < 16; ++dd)
                oacc[dd] += p * Vs[j][d0 + dd];
        }
    }

    float inv = 1.0f / l;
    float* op = o + base + (size_t)(qt * 64 + r) * HD + d0;
    #pragma unroll
    for (int i = 0; i < 4; ++i) {
        float4 ov;
        ov.x = oacc[i*4 + 0] * inv;
        ov.y = oacc[i*4 + 1] * inv;
        ov.z = oacc[i*4 + 2] * inv;
        ov.w = oacc[i*4 + 3] * inv;
        *(float4*)(op + i * 4) = ov;
    }
}

// ---------------------------------------------------------------------------
extern "C" void kernel_launch(void* const* d_in, const int* in_sizes, int n_in,
                              void* d_out, int out_size, void* d_ws, size_t ws_size,
                              hipStream_t stream) {
    const float* x    = (const float*)d_in[0];
    const float* w_q  = (const float*)d_in[1];
    const float* b_q  = (const float*)d_in[2];
    const float* w_k  = (const float*)d_in[3];
    const float* b_k  = (const float*)d_in[4];
    const float* w_v  = (const float*)d_in[5];
    const float* b_v  = (const float*)d_in[6];
    const float* g_q  = (const float*)d_in[7];
    const float* be_q = (const float*)d_in[8];
    const float* g_k  = (const float*)d_in[9];
    const float* be_k = (const float*)d_in[10];
    const float* w_o  = (const float*)d_in[11];
    const float* b_o  = (const float*)d_in[12];
    float* out = (float*)d_out;

    const int B = 2, N = 2048, C = 1024, H = 16, INNER = 1024;
    const int M = B * N;  // 4096

    // workspace: sx | q | k | v   (o reuses sx; total 64 MB)
    float* sx = (float*)d_ws;
    float* q  = sx + (size_t)M * C;
    float* k  = q  + (size_t)M * INNER;
    float* v  = k  + (size_t)M * INNER;
    float* o  = sx;  // sx dead after the three QKV GEMMs

    ln_silu_kernel<<<M, 256, 0, stream>>>(x, sx, C);

    dim3 ggrid(INNER / 64, M / 64);
    gemm_bias_kernel<false><<<ggrid, 256, 0, stream>>>(sx, w_q, b_q, q, M, INNER, C);
    gemm_bias_kernel<false><<<ggrid, 256, 0, stream>>>(sx, w_k, b_k, k, M, INNER, C);
    gemm_bias_kernel<false><<<ggrid, 256, 0, stream>>>(sx, w_v, b_v, v, M, INNER, C);

    // q = LN(q)*g+be, then * inner^-0.5 (= 1/32); k = LN(k)*g+be
    ln_affine_kernel<<<M, 256, 0, stream>>>(q, g_q, be_q, 0.03125f, INNER);
    ln_affine_kernel<<<M, 256, 0, stream>>>(k, g_k, be_k, 1.0f, INNER);

    dim3 fgrid(N / 64, H, B);
    flash_kernel<<<fgrid, 256, 0, stream>>>(q, k, v, o, N, INNER);

    dim3 ogrid(C / 64, M / 64);
    gemm_bias_kernel<true><<<ogrid, 256, 0, stream>>>(o, w_o, b_o, out, M, C, INNER);
}

// Round 2
// 277.642 us; speedup vs baseline: 4.9936x; 4.9936x over previous
//
#include <hip/hip_runtime.h>
#include <hip/hip_bf16.h>
#include <math.h>

#define LN_EPS 1e-5f

typedef __attribute__((ext_vector_type(8))) short bf16x8;
typedef __attribute__((ext_vector_type(8))) short short8;
typedef __attribute__((ext_vector_type(4))) float f32x4;
typedef unsigned short ushort_t;

__device__ __forceinline__ float silu_f(float x) {
    return x / (1.0f + __expf(-x));
}

__device__ __forceinline__ ushort_t f2bf(float f) {
    __hip_bfloat16 h = __float2bfloat16(f);
    return *reinterpret_cast<ushort_t*>(&h);
}

__device__ __forceinline__ float bf2f(ushort_t u) {
    __hip_bfloat16 h = *reinterpret_cast<__hip_bfloat16*>(&u);
    return __bfloat162float(h);
}

// async global->LDS 16B per lane. lds must be wave-uniform; dst = lds + lane*16.
__device__ __forceinline__ void gld16(const void* g, void* lds) {
    __builtin_amdgcn_global_load_lds(
        (const __attribute__((address_space(1))) unsigned int*)g,
        (__attribute__((address_space(3))) unsigned int*)lds, 16, 0, 0);
}

// Block-wide reduction of (sum, sumsq). blockDim.x == 256 (4 waves of 64).
__device__ __forceinline__ float2 block_reduce2(float2 p, float2* sbuf) {
    #pragma unroll
    for (int off = 32; off > 0; off >>= 1) {
        p.x += __shfl_down(p.x, off, 64);
        p.y += __shfl_down(p.y, off, 64);
    }
    int lane = threadIdx.x & 63;
    int wid  = threadIdx.x >> 6;
    if (lane == 0) sbuf[wid] = p;
    __syncthreads();
    if (threadIdx.x == 0) {
        float2 r = sbuf[0];
        for (int i = 1; i < 4; ++i) { r.x += sbuf[i].x; r.y += sbuf[i].y; }
        sbuf[0] = r;
    }
    __syncthreads();
    return sbuf[0];
}

// ---------------------------------------------------------------------------
// LN (no affine) + SiLU, fp32 in -> bf16 out. One block per row of 1024.
// ---------------------------------------------------------------------------
__global__ __launch_bounds__(256) void ln_silu_kernel(
    const float* __restrict__ x, ushort_t* __restrict__ out)
{
    __shared__ float2 sbuf[4];
    const int C = 1024;
    int row = blockIdx.x;
    const float4* xr = (const float4*)(x + (size_t)row * C);
    float4 v = xr[threadIdx.x];
    float2 p;
    p.x = v.x + v.y + v.z + v.w;
    p.y = v.x*v.x + v.y*v.y + v.z*v.z + v.w*v.w;
    float2 s = block_reduce2(p, sbuf);
    float mean = s.x / (float)C;
    float var  = s.y / (float)C - mean * mean;
    float rstd = rsqrtf(var + LN_EPS);
    ushort4 y;
    y.x = f2bf(silu_f((v.x - mean) * rstd));
    y.y = f2bf(silu_f((v.y - mean) * rstd));
    y.z = f2bf(silu_f((v.z - mean) * rstd));
    y.w = f2bf(silu_f((v.w - mean) * rstd));
    ((ushort4*)(out + (size_t)row * C))[threadIdx.x] = y;
}

// ---------------------------------------------------------------------------
// Affine LN in place on bf16 rows of 1024, then scale.
// ---------------------------------------------------------------------------
__global__ __launch_bounds__(256) void ln_affine_bf16(
    ushort_t* __restrict__ q, const float* __restrict__ g,
    const float* __restrict__ be, float scale)
{
    __shared__ float2 sbuf[4];
    const int C = 1024;
    int row = blockIdx.x;
    ushort4 u = ((ushort4*)(q + (size_t)row * C))[threadIdx.x];
    float v0 = bf2f(u.x), v1 = bf2f(u.y), v2 = bf2f(u.z), v3 = bf2f(u.w);
    float2 p;
    p.x = v0 + v1 + v2 + v3;
    p.y = v0*v0 + v1*v1 + v2*v2 + v3*v3;
    float2 s = block_reduce2(p, sbuf);
    float mean = s.x / (float)C;
    float var  = s.y / (float)C - mean * mean;
    float rstd = rsqrtf(var + LN_EPS);
    float4 gv = ((const float4*)g)[threadIdx.x];
    float4 bv = ((const float4*)be)[threadIdx.x];
    ushort4 y;
    y.x = f2bf(((v0 - mean) * rstd * gv.x + bv.x) * scale);
    y.y = f2bf(((v1 - mean) * rstd * gv.y + bv.y) * scale);
    y.z = f2bf(((v2 - mean) * rstd * gv.z + bv.z) * scale);
    y.w = f2bf(((v3 - mean) * rstd * gv.w + bv.w) * scale);
    ((ushort4*)(q + (size_t)row * C))[threadIdx.x] = y;
}

// ---------------------------------------------------------------------------
// Transpose 4 fp32 weight matrices [1024][1024] -> bf16 [N][K] (W^T).
// ---------------------------------------------------------------------------
struct W4 { const float* p[4]; };

__global__ __launch_bounds__(256) void transpose_w(W4 w, ushort_t* __restrict__ outbase)
{
    __shared__ float Ls[64][65];
    int z = blockIdx.z;
    const float* in = w.p[z];
    ushort_t* out = outbase + (size_t)z * 1024 * 1024;
    int r0 = blockIdx.y * 64, c0 = blockIdx.x * 64;
    int t = threadIdx.x, r = t >> 2, j = (t & 3) * 16;
    #pragma unroll
    for (int i = 0; i < 4; ++i) {
        float4 v = *(const float4*)(in + (size_t)(r0 + r) * 1024 + c0 + j + i * 4);
        Ls[r][j + i*4 + 0] = v.x;
        Ls[r][j + i*4 + 1] = v.y;
        Ls[r][j + i*4 + 2] = v.z;
        Ls[r][j + i*4 + 3] = v.w;
    }
    __syncthreads();
    __align__(16) ushort_t tmp[16];
    #pragma unroll
    for (int i = 0; i < 16; ++i) tmp[i] = f2bf(Ls[j + i][r]);
    ushort_t* op = out + (size_t)(c0 + r) * 1024 + r0 + j;
    *(short8*)(op)     = *(short8*)(tmp);
    *(short8*)(op + 8) = *(short8*)(tmp + 8);
}

// ---------------------------------------------------------------------------
// Batched bf16 transpose: in [b][2048][1024] -> out [b][1024][2048].
// Gives V^T layout [b][h*64+d][n].
// ---------------------------------------------------------------------------
__global__ __launch_bounds__(256) void transpose_v(
    const ushort_t* __restrict__ in, ushort_t* __restrict__ out)
{
    __shared__ ushort_t Ls[64][72];
    int b = blockIdx.z;
    const ushort_t* ib = in + (size_t)b * 2048 * 1024;
    ushort_t* ob = out + (size_t)b * 1024 * 2048;
    int r0 = blockIdx.y * 64, c0 = blockIdx.x * 64;  // r over n, c over (h*64+d)
    int t = threadIdx.x, r = t >> 2, j = (t & 3) * 16;
    const ushort_t* ip = ib + (size_t)(r0 + r) * 1024 + c0 + j;
    *(short8*)(&Ls[r][j])     = *(const short8*)(ip);
    *(short8*)(&Ls[r][j + 8]) = *(const short8*)(ip + 8);
    __syncthreads();
    __align__(16) ushort_t tmp[16];
    #pragma unroll
    for (int i = 0; i < 16; ++i) tmp[i] = Ls[j + i][r];
    ushort_t* op = ob + (size_t)(c0 + r) * 2048 + r0 + j;
    *(short8*)(op)     = *(short8*)(tmp);
    *(short8*)(op + 8) = *(short8*)(tmp + 8);
}

// ---------------------------------------------------------------------------
// bf16 MFMA GEMM: C[M,N] = A[M,K] @ Bt[N,K]^T + bias.
// BM x 128 tile, BK=64, 256 threads (4 waves, 2x2), 16x16x32 MFMA.
// global_load_lds staging with XOR chunk swizzle (LDS chunk c holds global
// chunk c^(row&7)) -> unpadded LDS, conflict-free ds_read_b128 frags.
// z-grid selects weight/bias/output (fused QKV).
// ---------------------------------------------------------------------------
template<int BM, bool OUT_BF16>
__global__ __launch_bounds__(256) void gemm_mfma(
    const ushort_t* __restrict__ A, const ushort_t* __restrict__ Bt0,
    const float* __restrict__ b0, const float* __restrict__ b1,
    const float* __restrict__ b2, void* __restrict__ out0,
    int M, int N, int K)
{
    constexpr int BK = 64;
    constexpr int MI = BM / 32;          // m-tiles of 16 per wave
    __shared__ ushort_t As[BM * BK];
    __shared__ ushort_t Bs[128 * BK];

    int z = blockIdx.z;
    const ushort_t* Bt = Bt0 + (size_t)z * N * K;
    const float* bias = (z == 0) ? b0 : (z == 1) ? b1 : b2;

    int t = threadIdx.x;
    int lane = t & 63, wv = t >> 6;
    int wr = wv >> 1, wc = wv & 1;
    int quad = lane >> 4, ln16 = lane & 15;

    int row0 = blockIdx.y * BM;
    int col0 = blockIdx.x * 128;

    const f32x4 zero4 = {0.f, 0.f, 0.f, 0.f};
    f32x4 acc[MI][4];
    #pragma unroll
    for (int i = 0; i < MI; ++i)
        #pragma unroll
        for (int j = 0; j < 4; ++j) acc[i][j] = zero4;

    for (int kt = 0; kt < K; kt += BK) {
        #pragma unroll
        for (int c = 0; c < BM / 32; ++c) {
            int idx = c * 256 + t;
            int r = idx >> 3, ch = idx & 7;
            int g = ch ^ (r & 7);
            gld16(A + (size_t)(row0 + r) * K + kt + g * 8,
                  As + (size_t)(c * 256 + wv * 64) * 8);
        }
        #pragma unroll
        for (int c = 0; c < 4; ++c) {
            int idx = c * 256 + t;
            int r = idx >> 3, ch = idx & 7;
            int g = ch ^ (r & 7);
            gld16(Bt + (size_t)(col0 + r) * K + kt + g * 8,
                  Bs + (size_t)(c * 256 + wv * 64) * 8);
        }
        __syncthreads();
        #pragma unroll
        for (int s = 0; s < 2; ++s) {
            bf16x8 af[MI], bf[4];
            int g = s * 4 + quad;
            #pragma unroll
            for (int i = 0; i < MI; ++i) {
                int m = wr * (BM / 2) + i * 16 + ln16;
                af[i] = *(const bf16x8*)(As + (size_t)(m * 8 + (g ^ (m & 7))) * 8);
            }
            #pragma unroll
            for (int j = 0; j < 4; ++j) {
                int n = wc * 64 + j * 16 + ln16;
                bf[j] = *(const bf16x8*)(Bs + (size_t)(n * 8 + (g ^ (n & 7))) * 8);
            }
            #pragma unroll
            for (int i = 0; i < MI; ++i)
                #pragma unroll
                for (int j = 0; j < 4; ++j)
                    acc[i][j] = __builtin_amdgcn_mfma_f32_16x16x32_bf16(
                        af[i], bf[j], acc[i][j], 0, 0, 0);
        }
        __syncthreads();
    }

    #pragma unroll
    for (int j = 0; j < 4; ++j) {
        int col = col0 + wc * 64 + j * 16 + ln16;
        float bv = bias[col];
        #pragma unroll
        for (int i = 0; i < MI; ++i) {
            int rowb = row0 + wr * (BM / 2) + i * 16 + quad * 4;
            #pragma unroll
            for (int r = 0; r < 4; ++r) {
                float val = acc[i][j][r] + bv;
                if (OUT_BF16) {
                    ushort_t* out = (ushort_t*)out0 + (size_t)z * M * N;
                    out[(size_t)(rowb + r) * N + col] = f2bf(val);
                } else {
                    float* out = (float*)out0;
                    out[(size_t)(rowb + r) * N + col] = val;
                }
            }
        }
    }
}

// ---------------------------------------------------------------------------
// MFMA flash attention. Block = 256 thr (4 waves x 16 Q rows), 64 Q rows per
// block, one (b,h). Key tiles of 64. q pre-scaled by inner^-0.5.
// Epilogue fuses SiLU, writes bf16.
// ---------------------------------------------------------------------------
__global__ __launch_bounds__(256) void flash_mfma(
    const ushort_t* __restrict__ qb, const ushort_t* __restrict__ kb,
    const ushort_t* __restrict__ vT, ushort_t* __restrict__ ob)
{
    const int N = 2048, HD = 1024, D = 64, H = 16;
    __shared__ ushort_t Ks[64 * 64];
    __shared__ ushort_t Vs[64 * 64];
    __shared__ ushort_t Ps[4 * 16 * 72];

    int t = threadIdx.x, lane = t & 63, wv = t >> 6;
    int quad = lane >> 4, ln16 = lane & 15;
    int qt = blockIdx.x, h = blockIdx.y, b = blockIdx.z;

    size_t qk_base = (size_t)b * N * HD + (size_t)h * D;
    size_t vt_base = (size_t)(b * H + h) * D * N;

    bf16x8 qf[2];
    {
        const ushort_t* qp = qb + qk_base + (size_t)(qt * 64 + wv * 16 + ln16) * HD;
        qf[0] = *(const bf16x8*)(qp + quad * 8);
        qf[1] = *(const bf16x8*)(qp + 32 + quad * 8);
    }

    const f32x4 zero4 = {0.f, 0.f, 0.f, 0.f};
    f32x4 oacc[4];
    #pragma unroll
    for (int j = 0; j < 4; ++j) oacc[j] = zero4;
    float mrow[4] = {-INFINITY, -INFINITY, -INFINITY, -INFINITY};
    float lrow[4] = {0.f, 0.f, 0.f, 0.f};

    for (int kt = 0; kt < N; kt += 64) {
        __syncthreads();   // all waves done reading Ks/Vs from previous iter
        #pragma unroll
        for (int c = 0; c < 2; ++c) {
            int idx = c * 256 + t;
            int r = idx >> 3, ch = idx & 7;
            int g = ch ^ (r & 7);
            gld16(kb + qk_base + (size_t)(kt + r) * HD + g * 8,
                  Ks + (size_t)(c * 256 + wv * 64) * 8);
            gld16(vT + vt_base + (size_t)r * N + kt + g * 8,
                  Vs + (size_t)(c * 256 + wv * 64) * 8);
        }
        __syncthreads();

        // S = Q @ K^T  (rows: this wave's 16 q rows; cols: 64 keys)
        f32x4 sacc[4];
        #pragma unroll
        for (int j = 0; j < 4; ++j) sacc[j] = zero4;
        #pragma unroll
        for (int s = 0; s < 2; ++s) {
            int g = s * 4 + quad;
            #pragma unroll
            for (int j = 0; j < 4; ++j) {
                int n = j * 16 + ln16;
                bf16x8 kf = *(const bf16x8*)(Ks + (size_t)(n * 8 + (g ^ (n & 7))) * 8);
                sacc[j] = __builtin_amdgcn_mfma_f32_16x16x32_bf16(qf[s], kf, sacc[j], 0, 0, 0);
            }
        }

        // online softmax; row = quad*4 + r, col = j*16 + ln16
        float pr[4][4];
        #pragma unroll
        for (int r = 0; r < 4; ++r) {
            float mx = fmaxf(fmaxf(sacc[0][r], sacc[1][r]), fmaxf(sacc[2][r], sacc[3][r]));
            mx = fmaxf(mx, __shfl_xor(mx, 1, 64));
            mx = fmaxf(mx, __shfl_xor(mx, 2, 64));
            mx = fmaxf(mx, __shfl_xor(mx, 4, 64));
            mx = fmaxf(mx, __shfl_xor(mx, 8, 64));
            float mnew = fmaxf(mrow[r], mx);
            float alpha = __expf(mrow[r] - mnew);
            float sum = 0.f;
            #pragma unroll
            for (int j = 0; j < 4; ++j) {
                float p = __expf(sacc[j][r] - mnew);
                pr[r][j] = p;
                sum += p;
            }
            sum += __shfl_xor(sum, 1, 64);
            sum += __shfl_xor(sum, 2, 64);
            sum += __shfl_xor(sum, 4, 64);
            sum += __shfl_xor(sum, 8, 64);
            lrow[r] = lrow[r] * alpha + sum;
            mrow[r] = mnew;
            #pragma unroll
            for (int j = 0; j < 4; ++j) oacc[j][r] *= alpha;
        }

        // P (C-layout) -> LDS in A-operand layout [m][key], padded rows of 72
        {
            ushort_t* pw = Ps + wv * 16 * 72;
            #pragma unroll
            for (int r = 0; r < 4; ++r)
                #pragma unroll
                for (int j = 0; j < 4; ++j)
                    pw[(quad * 4 + r) * 72 + j * 16 + ln16] = f2bf(pr[r][j]);
        }
        __syncthreads();   // safety: ensure P writes land before frag reads

        // O += P @ V  (A = P[m][key] from LDS, B = V^T[d][key] from Vs)
        #pragma unroll
        for (int s = 0; s < 2; ++s) {
            bf16x8 pf = *(const bf16x8*)(Ps + (size_t)(wv * 16 + ln16) * 72 + s * 32 + quad * 8);
            int g = s * 4 + quad;
            #pragma unroll
            for (int j = 0; j < 4; ++j) {
                int n = j * 16 + ln16;
                bf16x8 vf = *(const bf16x8*)(Vs + (size_t)(n * 8 + (g ^ (n & 7))) * 8);
                oacc[j] = __builtin_amdgcn_mfma_f32_16x16x32_bf16(pf, vf, oacc[j], 0, 0, 0);
            }
        }
    }

    // epilogue: O/l, SiLU, bf16 store
    #pragma unroll
    for (int r = 0; r < 4; ++r) {
        float inv = 1.0f / lrow[r];
        size_t rowoff = qk_base + (size_t)(qt * 64 + wv * 16 + quad * 4 + r) * HD;
        #pragma unroll
        for (int j = 0; j < 4; ++j) {
            float v = oacc[j][r] * inv;
            ob[rowoff + j * 16 + ln16] = f2bf(silu_f(v));
        }
    }
}

// ---------------------------------------------------------------------------
extern "C" void kernel_launch(void* const* d_in, const int* in_sizes, int n_in,
                              void* d_out, int out_size, void* d_ws, size_t ws_size,
                              hipStream_t stream) {
    const float* x    = (const float*)d_in[0];
    const float* w_q  = (const float*)d_in[1];
    const float* b_q  = (const float*)d_in[2];
    const float* w_k  = (const float*)d_in[3];
    const float* b_k  = (const float*)d_in[4];
    const float* w_v  = (const float*)d_in[5];
    const float* b_v  = (const float*)d_in[6];
    const float* g_q  = (const float*)d_in[7];
    const float* be_q = (const float*)d_in[8];
    const float* g_k  = (const float*)d_in[9];
    const float* be_k = (const float*)d_in[10];
    const float* w_o  = (const float*)d_in[11];
    const float* b_o  = (const float*)d_in[12];
    float* out = (float*)d_out;

    const int B = 2, N = 2048, C = 1024, H = 16, INNER = 1024;
    const int M = B * N;                       // 4096
    const size_t MC = (size_t)M * C;           // 4194304

    // ws layout (ushort elems): sx | qkv(3x) | vT | wT(4x)   = 48 MB
    ushort_t* ws  = (ushort_t*)d_ws;
    ushort_t* sx  = ws;                        // [M][1024] bf16 (later reused as o)
    ushort_t* qkv = ws + MC;                   // [3][M][1024]
    ushort_t* vTp = ws + 4 * MC;               // [B][1024][2048]
    ushort_t* wT  = ws + 5 * MC;               // [4][1024][1024]

    ushort_t* qbuf = qkv;
    ushort_t* kbuf = qkv + MC;
    ushort_t* vbuf = qkv + 2 * MC;
    ushort_t* obuf = sx;                       // sx dead after QKV GEMM

    // 1. weight transposes fp32 [K][N] -> bf16 [N][K]
    W4 w4; w4.p[0] = w_q; w4.p[1] = w_k; w4.p[2] = w_v; w4.p[3] = w_o;
    transpose_w<<<dim3(16, 16, 4), 256, 0, stream>>>(w4, wT);

    // 2. pre-norm + SiLU -> bf16
    ln_silu_kernel<<<M, 256, 0, stream>>>(x, sx);

    // 3. fused QKV GEMM (bf16 out, bias)
    gemm_mfma<128, true><<<dim3(INNER / 128, M / 128, 3), 256, 0, stream>>>(
        sx, wT, b_q, b_k, b_v, qkv, M, INNER, C);

    // 4. q/k layernorms (bf16 in place); q also scaled by inner^-0.5
    ln_affine_bf16<<<M, 256, 0, stream>>>(qbuf, g_q, be_q, 0.03125f);
    ln_affine_bf16<<<M, 256, 0, stream>>>(kbuf, g_k, be_k, 1.0f);

    // 5. V^T: [b][n][h*64+d] -> [b][h*64+d][n]
    transpose_v<<<dim3(16, 32, 2), 256, 0, stream>>>(vbuf, vTp);

    // 6. flash attention (writes silu(o) bf16 into obuf)
    flash_mfma<<<dim3(N / 64, H, B), 256, 0, stream>>>(qbuf, kbuf, vTp, obuf);

    // 7. final GEMM -> fp32 out
    gemm_mfma<64, false><<<dim3(C / 128, M / 64, 1), 256, 0, stream>>>(
        obuf, wT + (size_t)3 * 1024 * 1024, b_o, b_o, b_o, out, M, C, INNER);
}

// Round 3
// 246.277 us; speedup vs baseline: 5.6296x; 1.1274x over previous
//
#include <hip/hip_runtime.h>
#include <hip/hip_bf16.h>
#include <math.h>

#define LN_EPS 1e-5f

typedef __attribute__((ext_vector_type(8))) short bf16x8;
typedef __attribute__((ext_vector_type(8))) short short8;
typedef __attribute__((ext_vector_type(4))) float f32x4;
typedef unsigned short ushort_t;

__device__ __forceinline__ float silu_f(float x) {
    return x / (1.0f + __expf(-x));
}

__device__ __forceinline__ ushort_t f2bf(float f) {
    __hip_bfloat16 h = __float2bfloat16(f);
    return *reinterpret_cast<ushort_t*>(&h);
}

__device__ __forceinline__ float bf2f(ushort_t u) {
    __hip_bfloat16 h = *reinterpret_cast<__hip_bfloat16*>(&u);
    return __bfloat162float(h);
}

// async global->LDS 16B per lane. lds must be wave-uniform; dst = lds + lane*16.
__device__ __forceinline__ void gld16(const void* g, void* lds) {
    __builtin_amdgcn_global_load_lds(
        (const __attribute__((address_space(1))) unsigned int*)g,
        (__attribute__((address_space(3))) unsigned int*)lds, 16, 0, 0);
}

// Block-wide reduction of (sum, sumsq). blockDim.x == 256 (4 waves of 64).
__device__ __forceinline__ float2 block_reduce2(float2 p, float2* sbuf) {
    #pragma unroll
    for (int off = 32; off > 0; off >>= 1) {
        p.x += __shfl_down(p.x, off, 64);
        p.y += __shfl_down(p.y, off, 64);
    }
    int lane = threadIdx.x & 63;
    int wid  = threadIdx.x >> 6;
    if (lane == 0) sbuf[wid] = p;
    __syncthreads();
    if (threadIdx.x == 0) {
        float2 r = sbuf[0];
        for (int i = 1; i < 4; ++i) { r.x += sbuf[i].x; r.y += sbuf[i].y; }
        sbuf[0] = r;
    }
    __syncthreads();
    return sbuf[0];
}

// ---------------------------------------------------------------------------
// LN (no affine) + SiLU, fp32 in -> bf16 out. One block per row of 1024.
// ---------------------------------------------------------------------------
__global__ __launch_bounds__(256) void ln_silu_kernel(
    const float* __restrict__ x, ushort_t* __restrict__ out)
{
    __shared__ float2 sbuf[4];
    const int C = 1024;
    int row = blockIdx.x;
    const float4* xr = (const float4*)(x + (size_t)row * C);
    float4 v = xr[threadIdx.x];
    float2 p;
    p.x = v.x + v.y + v.z + v.w;
    p.y = v.x*v.x + v.y*v.y + v.z*v.z + v.w*v.w;
    float2 s = block_reduce2(p, sbuf);
    float mean = s.x / (float)C;
    float var  = s.y / (float)C - mean * mean;
    float rstd = rsqrtf(var + LN_EPS);
    ushort4 y;
    y.x = f2bf(silu_f((v.x - mean) * rstd));
    y.y = f2bf(silu_f((v.y - mean) * rstd));
    y.z = f2bf(silu_f((v.z - mean) * rstd));
    y.w = f2bf(silu_f((v.w - mean) * rstd));
    ((ushort4*)(out + (size_t)row * C))[threadIdx.x] = y;
}

// ---------------------------------------------------------------------------
// Affine LN in place on bf16 rows of 1024, then scale.
// ---------------------------------------------------------------------------
__global__ __launch_bounds__(256) void ln_affine_bf16(
    ushort_t* __restrict__ q, const float* __restrict__ g,
    const float* __restrict__ be, float scale)
{
    __shared__ float2 sbuf[4];
    const int C = 1024;
    int row = blockIdx.x;
    ushort4 u = ((ushort4*)(q + (size_t)row * C))[threadIdx.x];
    float v0 = bf2f(u.x), v1 = bf2f(u.y), v2 = bf2f(u.z), v3 = bf2f(u.w);
    float2 p;
    p.x = v0 + v1 + v2 + v3;
    p.y = v0*v0 + v1*v1 + v2*v2 + v3*v3;
    float2 s = block_reduce2(p, sbuf);
    float mean = s.x / (float)C;
    float var  = s.y / (float)C - mean * mean;
    float rstd = rsqrtf(var + LN_EPS);
    float4 gv = ((const float4*)g)[threadIdx.x];
    float4 bv = ((const float4*)be)[threadIdx.x];
    ushort4 y;
    y.x = f2bf(((v0 - mean) * rstd * gv.x + bv.x) * scale);
    y.y = f2bf(((v1 - mean) * rstd * gv.y + bv.y) * scale);
    y.z = f2bf(((v2 - mean) * rstd * gv.z + bv.z) * scale);
    y.w = f2bf(((v3 - mean) * rstd * gv.w + bv.w) * scale);
    ((ushort4*)(q + (size_t)row * C))[threadIdx.x] = y;
}

// ---------------------------------------------------------------------------
// Transpose 4 fp32 weight matrices [1024][1024] -> bf16 [N][K] (W^T).
// ---------------------------------------------------------------------------
struct W4 { const float* p[4]; };

__global__ __launch_bounds__(256) void transpose_w(W4 w, ushort_t* __restrict__ outbase)
{
    __shared__ float Ls[64][65];
    int z = blockIdx.z;
    const float* in = w.p[z];
    ushort_t* out = outbase + (size_t)z * 1024 * 1024;
    int r0 = blockIdx.y * 64, c0 = blockIdx.x * 64;
    int t = threadIdx.x, r = t >> 2, j = (t & 3) * 16;
    #pragma unroll
    for (int i = 0; i < 4; ++i) {
        float4 v = *(const float4*)(in + (size_t)(r0 + r) * 1024 + c0 + j + i * 4);
        Ls[r][j + i*4 + 0] = v.x;
        Ls[r][j + i*4 + 1] = v.y;
        Ls[r][j + i*4 + 2] = v.z;
        Ls[r][j + i*4 + 3] = v.w;
    }
    __syncthreads();
    __align__(16) ushort_t tmp[16];
    #pragma unroll
    for (int i = 0; i < 16; ++i) tmp[i] = f2bf(Ls[j + i][r]);
    ushort_t* op = out + (size_t)(c0 + r) * 1024 + r0 + j;
    *(short8*)(op)     = *(short8*)(tmp);
    *(short8*)(op + 8) = *(short8*)(tmp + 8);
}

// ---------------------------------------------------------------------------
// Batched bf16 transpose: in [b][2048][1024] -> out [b][1024][2048].
// Gives V^T layout [b][h*64+d][n].
// ---------------------------------------------------------------------------
__global__ __launch_bounds__(256) void transpose_v(
    const ushort_t* __restrict__ in, ushort_t* __restrict__ out)
{
    __shared__ ushort_t Ls[64][72];
    int b = blockIdx.z;
    const ushort_t* ib = in + (size_t)b * 2048 * 1024;
    ushort_t* ob = out + (size_t)b * 1024 * 2048;
    int r0 = blockIdx.y * 64, c0 = blockIdx.x * 64;  // r over n, c over (h*64+d)
    int t = threadIdx.x, r = t >> 2, j = (t & 3) * 16;
    const ushort_t* ip = ib + (size_t)(r0 + r) * 1024 + c0 + j;
    *(short8*)(&Ls[r][j])     = *(const short8*)(ip);
    *(short8*)(&Ls[r][j + 8]) = *(const short8*)(ip + 8);
    __syncthreads();
    __align__(16) ushort_t tmp[16];
    #pragma unroll
    for (int i = 0; i < 16; ++i) tmp[i] = Ls[j + i][r];
    ushort_t* op = ob + (size_t)(c0 + r) * 2048 + r0 + j;
    *(short8*)(op)     = *(short8*)(tmp);
    *(short8*)(op + 8) = *(short8*)(tmp + 8);
}

// ---------------------------------------------------------------------------
// bf16 MFMA GEMM: C[M,N] = A[M,K] @ Bt[N,K]^T + bias.
// BM x 128 tile, BK=64, 256 threads (4 waves, 2x2), 16x16x32 MFMA.
// global_load_lds staging with XOR chunk swizzle. z-grid selects weight/bias
// (fused QKV).
// ---------------------------------------------------------------------------
template<int BM, bool OUT_BF16>
__global__ __launch_bounds__(256) void gemm_mfma(
    const ushort_t* __restrict__ A, const ushort_t* __restrict__ Bt0,
    const float* __restrict__ b0, const float* __restrict__ b1,
    const float* __restrict__ b2, void* __restrict__ out0,
    int M, int N, int K)
{
    constexpr int BK = 64;
    constexpr int MI = BM / 32;          // m-tiles of 16 per wave
    __shared__ ushort_t As[BM * BK];
    __shared__ ushort_t Bs[128 * BK];

    int z = blockIdx.z;
    const ushort_t* Bt = Bt0 + (size_t)z * N * K;
    const float* bias = (z == 0) ? b0 : (z == 1) ? b1 : b2;

    int t = threadIdx.x;
    int lane = t & 63, wv = t >> 6;
    int wr = wv >> 1, wc = wv & 1;
    int quad = lane >> 4, ln16 = lane & 15;

    int row0 = blockIdx.y * BM;
    int col0 = blockIdx.x * 128;

    const f32x4 zero4 = {0.f, 0.f, 0.f, 0.f};
    f32x4 acc[MI][4];
    #pragma unroll
    for (int i = 0; i < MI; ++i)
        #pragma unroll
        for (int j = 0; j < 4; ++j) acc[i][j] = zero4;

    for (int kt = 0; kt < K; kt += BK) {
        #pragma unroll
        for (int c = 0; c < BM / 32; ++c) {
            int idx = c * 256 + t;
            int r = idx >> 3, ch = idx & 7;
            int g = ch ^ (r & 7);
            gld16(A + (size_t)(row0 + r) * K + kt + g * 8,
                  As + (size_t)(c * 256 + wv * 64) * 8);
        }
        #pragma unroll
        for (int c = 0; c < 4; ++c) {
            int idx = c * 256 + t;
            int r = idx >> 3, ch = idx & 7;
            int g = ch ^ (r & 7);
            gld16(Bt + (size_t)(col0 + r) * K + kt + g * 8,
                  Bs + (size_t)(c * 256 + wv * 64) * 8);
        }
        __syncthreads();
        #pragma unroll
        for (int s = 0; s < 2; ++s) {
            bf16x8 af[MI], bf[4];
            int g = s * 4 + quad;
            #pragma unroll
            for (int i = 0; i < MI; ++i) {
                int m = wr * (BM / 2) + i * 16 + ln16;
                af[i] = *(const bf16x8*)(As + (size_t)(m * 8 + (g ^ (m & 7))) * 8);
            }
            #pragma unroll
            for (int j = 0; j < 4; ++j) {
                int n = wc * 64 + j * 16 + ln16;
                bf[j] = *(const bf16x8*)(Bs + (size_t)(n * 8 + (g ^ (n & 7))) * 8);
            }
            #pragma unroll
            for (int i = 0; i < MI; ++i)
                #pragma unroll
                for (int j = 0; j < 4; ++j)
                    acc[i][j] = __builtin_amdgcn_mfma_f32_16x16x32_bf16(
                        af[i], bf[j], acc[i][j], 0, 0, 0);
        }
        __syncthreads();
    }

    #pragma unroll
    for (int j = 0; j < 4; ++j) {
        int col = col0 + wc * 64 + j * 16 + ln16;
        float bv = bias[col];
        #pragma unroll
        for (int i = 0; i < MI; ++i) {
            int rowb = row0 + wr * (BM / 2) + i * 16 + quad * 4;
            #pragma unroll
            for (int r = 0; r < 4; ++r) {
                float val = acc[i][j][r] + bv;
                if (OUT_BF16) {
                    ushort_t* out = (ushort_t*)out0 + (size_t)z * M * N;
                    out[(size_t)(rowb + r) * N + col] = f2bf(val);
                } else {
                    float* out = (float*)out0;
                    out[(size_t)(rowb + r) * N + col] = val;
                }
            }
        }
    }
}

// ---------------------------------------------------------------------------
// MFMA flash attention, S^T formulation.
// Block = 256 thr (4 waves x 16 Q rows), 64 Q rows per block, one (b,h).
// Key tiles of 128. S^T = mfma(K_frag, Q_frag): each lane owns ONE q-row
// (ln16); softmax is in-thread + 2 cross-quad shuffles. P written row-major
// (packed b64), read back as A-frags for PV. Epilogue fuses SiLU -> bf16.
// ---------------------------------------------------------------------------
__global__ __launch_bounds__(256) void flash_mfma(
    const ushort_t* __restrict__ qb, const ushort_t* __restrict__ kb,
    const ushort_t* __restrict__ vT, ushort_t* __restrict__ ob)
{
    const int N = 2048, HD = 1024, D = 64, H = 16;
    const int KT = 128;
    const int PP = 136;                    // P row pitch (128 + 8 pad)
    __shared__ ushort_t Ks[128 * 64];      // [key][d]
    __shared__ ushort_t Vs[64 * 128];      // [d][key]
    __shared__ ushort_t Ps[4][16 * PP];    // per-wave P[m][key]

    int t = threadIdx.x, lane = t & 63, wv = t >> 6;
    int quad = lane >> 4, ln16 = lane & 15;
    int qt = blockIdx.x, h = blockIdx.y, b = blockIdx.z;

    size_t qk_base = (size_t)b * N * HD + (size_t)h * D;
    size_t vt_base = (size_t)(b * H + h) * D * N;

    // Q fragment for this wave's 16 rows: Q[row=ln16][d = s*32 + quad*8 ..]
    bf16x8 qf[2];
    {
        const ushort_t* qp = qb + qk_base + (size_t)(qt * 64 + wv * 16 + ln16) * HD;
        qf[0] = *(const bf16x8*)(qp + quad * 8);
        qf[1] = *(const bf16x8*)(qp + 32 + quad * 8);
    }

    const f32x4 zero4 = {0.f, 0.f, 0.f, 0.f};
    f32x4 oacc[4];                          // O[row=quad*4+r][d=j*16+ln16]
    #pragma unroll
    for (int j = 0; j < 4; ++j) oacc[j] = zero4;
    float mcur = -INFINITY, lcur = 0.f;     // state for q-row ln16 (dup x4 quads)

    for (int kt = 0; kt < N; kt += KT) {
        __syncthreads();   // all waves done with previous Ks/Vs
        // stage K tile: 128 keys x 64 d (8-chunk xor swizzle per row)
        #pragma unroll
        for (int c = 0; c < 4; ++c) {
            int idx = c * 256 + t;
            int r = idx >> 3, ch = idx & 7, g = ch ^ (r & 7);
            gld16(kb + qk_base + (size_t)(kt + r) * HD + g * 8,
                  Ks + (size_t)(c * 256 + wv * 64) * 8);
        }
        // stage V^T tile: 64 d x 128 keys (16-chunk xor swizzle per row)
        #pragma unroll
        for (int c = 0; c < 4; ++c) {
            int idx = c * 256 + t;
            int r = idx >> 4, ch = idx & 15, g = ch ^ (r & 15);
            gld16(vT + vt_base + (size_t)r * N + kt + g * 8,
                  Vs + (size_t)(c * 256 + wv * 64) * 8);
        }
        __syncthreads();

        // S^T = K @ Q^T : 8 key-tiles, C-layout row=key(quad*4+r), col=q-row(ln16)
        f32x4 st[8];
        #pragma unroll
        for (int j = 0; j < 8; ++j) st[j] = zero4;
        #pragma unroll
        for (int s = 0; s < 2; ++s) {
            int g = s * 4 + quad;
            #pragma unroll
            for (int j = 0; j < 8; ++j) {
                int n = j * 16 + ln16;   // key row in Ks
                bf16x8 kf = *(const bf16x8*)(Ks + ((size_t)n * 8 + (g ^ (n & 7))) * 8);
                st[j] = __builtin_amdgcn_mfma_f32_16x16x32_bf16(kf, qf[s], st[j], 0, 0, 0);
            }
        }

        // online softmax for q-row ln16: 32 scores in-thread
        float mx = st[0][0];
        #pragma unroll
        for (int j = 0; j < 8; ++j) {
            float a = fmaxf(fmaxf(st[j][0], st[j][1]), fmaxf(st[j][2], st[j][3]));
            mx = fmaxf(mx, a);
        }
        mx = fmaxf(mx, __shfl_xor(mx, 16, 64));
        mx = fmaxf(mx, __shfl_xor(mx, 32, 64));
        float mnew = fmaxf(mcur, mx);
        float alpha = __expf(mcur - mnew);
        mcur = mnew;

        float psum = 0.f;
        ushort_t* pw = Ps[wv] + ln16 * PP;
        #pragma unroll
        for (int j = 0; j < 8; ++j) {
            float p0 = __expf(st[j][0] - mnew);
            float p1 = __expf(st[j][1] - mnew);
            float p2 = __expf(st[j][2] - mnew);
            float p3 = __expf(st[j][3] - mnew);
            psum += (p0 + p1) + (p2 + p3);
            ushort4 pk;
            pk.x = f2bf(p0); pk.y = f2bf(p1); pk.z = f2bf(p2); pk.w = f2bf(p3);
            *(ushort4*)(pw + j * 16 + quad * 4) = pk;   // P[ln16][key j*16+quad*4..+3]
        }
        psum += __shfl_xor(psum, 16, 64);
        psum += __shfl_xor(psum, 32, 64);
        lcur = lcur * alpha + psum;

        // alpha for the rows this lane accumulates (quad*4+r)
        float arow[4];
        #pragma unroll
        for (int r = 0; r < 4; ++r) arow[r] = __shfl(alpha, quad * 4 + r, 64);
        #pragma unroll
        for (int j = 0; j < 4; ++j) {
            oacc[j][0] *= arow[0]; oacc[j][1] *= arow[1];
            oacc[j][2] *= arow[2]; oacc[j][3] *= arow[3];
        }

        // O += P @ V : A = P[m][key] from LDS (same-wave dep, no barrier),
        // B = V^T frag from Vs.
        #pragma unroll
        for (int s = 0; s < 4; ++s) {
            bf16x8 pf = *(const bf16x8*)(Ps[wv] + (size_t)ln16 * PP + s * 32 + quad * 8);
            #pragma unroll
            for (int j = 0; j < 4; ++j) {
                int n = j * 16 + ln16;   // d row in Vs
                bf16x8 vf = *(const bf16x8*)(Vs + ((size_t)n * 16 + ((s * 4 + quad) ^ (n & 15))) * 8);
                oacc[j] = __builtin_amdgcn_mfma_f32_16x16x32_bf16(pf, vf, oacc[j], 0, 0, 0);
            }
        }
    }

    // epilogue: O/l, SiLU, bf16 store
    float lrows[4];
    #pragma unroll
    for (int r = 0; r < 4; ++r) lrows[r] = __shfl(lcur, quad * 4 + r, 64);
    #pragma unroll
    for (int r = 0; r < 4; ++r) {
        float inv = 1.0f / lrows[r];
        size_t rowoff = qk_base + (size_t)(qt * 64 + wv * 16 + quad * 4 + r) * HD;
        #pragma unroll
        for (int j = 0; j < 4; ++j) {
            float v = oacc[j][r] * inv;
            ob[rowoff + j * 16 + ln16] = f2bf(silu_f(v));
        }
    }
}

// ---------------------------------------------------------------------------
extern "C" void kernel_launch(void* const* d_in, const int* in_sizes, int n_in,
                              void* d_out, int out_size, void* d_ws, size_t ws_size,
                              hipStream_t stream) {
    const float* x    = (const float*)d_in[0];
    const float* w_q  = (const float*)d_in[1];
    const float* b_q  = (const float*)d_in[2];
    const float* w_k  = (const float*)d_in[3];
    const float* b_k  = (const float*)d_in[4];
    const float* w_v  = (const float*)d_in[5];
    const float* b_v  = (const float*)d_in[6];
    const float* g_q  = (const float*)d_in[7];
    const float* be_q = (const float*)d_in[8];
    const float* g_k  = (const float*)d_in[9];
    const float* be_k = (const float*)d_in[10];
    const float* w_o  = (const float*)d_in[11];
    const float* b_o  = (const float*)d_in[12];
    float* out = (float*)d_out;

    const int B = 2, N = 2048, C = 1024, H = 16, INNER = 1024;
    const int M = B * N;                       // 4096
    const size_t MC = (size_t)M * C;           // 4194304

    // ws layout (ushort elems): sx | qkv(3x) | vT | wT(4x)   = 48 MB
    ushort_t* ws  = (ushort_t*)d_ws;
    ushort_t* sx  = ws;                        // [M][1024] bf16 (later reused as o)
    ushort_t* qkv = ws + MC;                   // [3][M][1024]
    ushort_t* vTp = ws + 4 * MC;               // [B][1024][2048]
    ushort_t* wT  = ws + 5 * MC;               // [4][1024][1024]

    ushort_t* qbuf = qkv;
    ushort_t* kbuf = qkv + MC;
    ushort_t* vbuf = qkv + 2 * MC;
    ushort_t* obuf = sx;                       // sx dead after QKV GEMM

    // 1. weight transposes fp32 [K][N] -> bf16 [N][K]
    W4 w4; w4.p[0] = w_q; w4.p[1] = w_k; w4.p[2] = w_v; w4.p[3] = w_o;
    transpose_w<<<dim3(16, 16, 4), 256, 0, stream>>>(w4, wT);

    // 2. pre-norm + SiLU -> bf16
    ln_silu_kernel<<<M, 256, 0, stream>>>(x, sx);

    // 3. fused QKV GEMM (bf16 out, bias)
    gemm_mfma<128, true><<<dim3(INNER / 128, M / 128, 3), 256, 0, stream>>>(
        sx, wT, b_q, b_k, b_v, qkv, M, INNER, C);

    // 4. q/k layernorms (bf16 in place); q also scaled by inner^-0.5
    ln_affine_bf16<<<M, 256, 0, stream>>>(qbuf, g_q, be_q, 0.03125f);
    ln_affine_bf16<<<M, 256, 0, stream>>>(kbuf, g_k, be_k, 1.0f);

    // 5. V^T: [b][n][h*64+d] -> [b][h*64+d][n]
    transpose_v<<<dim3(16, 32, 2), 256, 0, stream>>>(vbuf, vTp);

    // 6. flash attention (writes silu(o) bf16 into obuf)
    flash_mfma<<<dim3(N / 64, H, B), 256, 0, stream>>>(qbuf, kbuf, vTp, obuf);

    // 7. final GEMM -> fp32 out
    gemm_mfma<64, false><<<dim3(C / 128, M / 64, 1), 256, 0, stream>>>(
        obuf, wT + (size_t)3 * 1024 * 1024, b_o, b_o, b_o, out, M, C, INNER);
}

// Round 4
// 242.151 us; speedup vs baseline: 5.7255x; 1.0170x over previous
//
#include <hip/hip_runtime.h>
#include <hip/hip_bf16.h>
#include <math.h>

#define LN_EPS 1e-5f

typedef __attribute__((ext_vector_type(8))) short bf16x8;
typedef __attribute__((ext_vector_type(4))) short bf16x4;
typedef __attribute__((ext_vector_type(8))) short short8;
typedef __attribute__((ext_vector_type(4))) float f32x4;
typedef unsigned short ushort_t;

__device__ __forceinline__ float silu_f(float x) {
    return x / (1.0f + __expf(-x));
}

__device__ __forceinline__ ushort_t f2bf(float f) {
    __hip_bfloat16 h = __float2bfloat16(f);
    return *reinterpret_cast<ushort_t*>(&h);
}

__device__ __forceinline__ float bf2f(ushort_t u) {
    __hip_bfloat16 h = *reinterpret_cast<__hip_bfloat16*>(&u);
    return __bfloat162float(h);
}

// pack two f32 -> one dword of 2 bf16 (lo = a, hi = b)
__device__ __forceinline__ unsigned pk2(float a, float b) {
#if defined(__has_builtin)
#if __has_builtin(__builtin_amdgcn_cvt_pk_bf16_f32)
    return __builtin_bit_cast(unsigned, __builtin_amdgcn_cvt_pk_bf16_f32(a, b));
#else
    return (((unsigned)f2bf(b)) << 16) | (unsigned)f2bf(a);
#endif
#else
    return (((unsigned)f2bf(b)) << 16) | (unsigned)f2bf(a);
#endif
}

// 16x16x16 bf16 MFMA (K=16): A regs 2, B regs 2, C/D 4.
__device__ __forceinline__ f32x4 mfma16(bf16x4 a, bf16x4 b, f32x4 c) {
#if defined(__has_builtin)
#if __has_builtin(__builtin_amdgcn_mfma_f32_16x16x16bf16_1k)
    return __builtin_amdgcn_mfma_f32_16x16x16bf16_1k(a, b, c, 0, 0, 0);
#elif __has_builtin(__builtin_amdgcn_mfma_f32_16x16x16_bf16)
    return __builtin_amdgcn_mfma_f32_16x16x16_bf16(a, b, c, 0, 0, 0);
#else
    f32x4 d = c;
    asm volatile("v_mfma_f32_16x16x16_bf16 %0, %1, %2, %0"
                 : "+v"(d) : "v"(a), "v"(b));
    return d;
#endif
#else
    f32x4 d = c;
    asm volatile("v_mfma_f32_16x16x16_bf16 %0, %1, %2, %0"
                 : "+v"(d) : "v"(a), "v"(b));
    return d;
#endif
}

// async global->LDS 16B per lane. lds must be wave-uniform; dst = lds + lane*16.
__device__ __forceinline__ void gld16(const void* g, void* lds) {
    __builtin_amdgcn_global_load_lds(
        (const __attribute__((address_space(1))) unsigned int*)g,
        (__attribute__((address_space(3))) unsigned int*)lds, 16, 0, 0);
}

// Block-wide reduction of (sum, sumsq). blockDim.x == 256 (4 waves of 64).
__device__ __forceinline__ float2 block_reduce2(float2 p, float2* sbuf) {
    #pragma unroll
    for (int off = 32; off > 0; off >>= 1) {
        p.x += __shfl_down(p.x, off, 64);
        p.y += __shfl_down(p.y, off, 64);
    }
    int lane = threadIdx.x & 63;
    int wid  = threadIdx.x >> 6;
    if (lane == 0) sbuf[wid] = p;
    __syncthreads();
    if (threadIdx.x == 0) {
        float2 r = sbuf[0];
        for (int i = 1; i < 4; ++i) { r.x += sbuf[i].x; r.y += sbuf[i].y; }
        sbuf[0] = r;
    }
    __syncthreads();
    return sbuf[0];
}

// ---------------------------------------------------------------------------
// LN (no affine) + SiLU, fp32 in -> bf16 out. One block per row of 1024.
// ---------------------------------------------------------------------------
__global__ __launch_bounds__(256) void ln_silu_kernel(
    const float* __restrict__ x, ushort_t* __restrict__ out)
{
    __shared__ float2 sbuf[4];
    const int C = 1024;
    int row = blockIdx.x;
    const float4* xr = (const float4*)(x + (size_t)row * C);
    float4 v = xr[threadIdx.x];
    float2 p;
    p.x = v.x + v.y + v.z + v.w;
    p.y = v.x*v.x + v.y*v.y + v.z*v.z + v.w*v.w;
    float2 s = block_reduce2(p, sbuf);
    float mean = s.x / (float)C;
    float var  = s.y / (float)C - mean * mean;
    float rstd = rsqrtf(var + LN_EPS);
    ushort4 y;
    y.x = f2bf(silu_f((v.x - mean) * rstd));
    y.y = f2bf(silu_f((v.y - mean) * rstd));
    y.z = f2bf(silu_f((v.z - mean) * rstd));
    y.w = f2bf(silu_f((v.w - mean) * rstd));
    ((ushort4*)(out + (size_t)row * C))[threadIdx.x] = y;
}

// ---------------------------------------------------------------------------
// Affine LN in place on bf16 rows of 1024, then scale.
// ---------------------------------------------------------------------------
__global__ __launch_bounds__(256) void ln_affine_bf16(
    ushort_t* __restrict__ q, const float* __restrict__ g,
    const float* __restrict__ be, float scale)
{
    __shared__ float2 sbuf[4];
    const int C = 1024;
    int row = blockIdx.x;
    ushort4 u = ((ushort4*)(q + (size_t)row * C))[threadIdx.x];
    float v0 = bf2f(u.x), v1 = bf2f(u.y), v2 = bf2f(u.z), v3 = bf2f(u.w);
    float2 p;
    p.x = v0 + v1 + v2 + v3;
    p.y = v0*v0 + v1*v1 + v2*v2 + v3*v3;
    float2 s = block_reduce2(p, sbuf);
    float mean = s.x / (float)C;
    float var  = s.y / (float)C - mean * mean;
    float rstd = rsqrtf(var + LN_EPS);
    float4 gv = ((const float4*)g)[threadIdx.x];
    float4 bv = ((const float4*)be)[threadIdx.x];
    ushort4 y;
    y.x = f2bf(((v0 - mean) * rstd * gv.x + bv.x) * scale);
    y.y = f2bf(((v1 - mean) * rstd * gv.y + bv.y) * scale);
    y.z = f2bf(((v2 - mean) * rstd * gv.z + bv.z) * scale);
    y.w = f2bf(((v3 - mean) * rstd * gv.w + bv.w) * scale);
    ((ushort4*)(q + (size_t)row * C))[threadIdx.x] = y;
}

// ---------------------------------------------------------------------------
// Transpose 4 fp32 weight matrices [1024][1024] -> bf16 [N][K] (W^T).
// ---------------------------------------------------------------------------
struct W4 { const float* p[4]; };

__global__ __launch_bounds__(256) void transpose_w(W4 w, ushort_t* __restrict__ outbase)
{
    __shared__ float Ls[64][65];
    int z = blockIdx.z;
    const float* in = w.p[z];
    ushort_t* out = outbase + (size_t)z * 1024 * 1024;
    int r0 = blockIdx.y * 64, c0 = blockIdx.x * 64;
    int t = threadIdx.x, r = t >> 2, j = (t & 3) * 16;
    #pragma unroll
    for (int i = 0; i < 4; ++i) {
        float4 v = *(const float4*)(in + (size_t)(r0 + r) * 1024 + c0 + j + i * 4);
        Ls[r][j + i*4 + 0] = v.x;
        Ls[r][j + i*4 + 1] = v.y;
        Ls[r][j + i*4 + 2] = v.z;
        Ls[r][j + i*4 + 3] = v.w;
    }
    __syncthreads();
    __align__(16) ushort_t tmp[16];
    #pragma unroll
    for (int i = 0; i < 16; ++i) tmp[i] = f2bf(Ls[j + i][r]);
    ushort_t* op = out + (size_t)(c0 + r) * 1024 + r0 + j;
    *(short8*)(op)     = *(short8*)(tmp);
    *(short8*)(op + 8) = *(short8*)(tmp + 8);
}

// ---------------------------------------------------------------------------
// Batched bf16 transpose: in [b][2048][1024] -> out [b][1024][2048].
// Gives V^T layout [b][h*64+d][n].
// ---------------------------------------------------------------------------
__global__ __launch_bounds__(256) void transpose_v(
    const ushort_t* __restrict__ in, ushort_t* __restrict__ out)
{
    __shared__ ushort_t Ls[64][72];
    int b = blockIdx.z;
    const ushort_t* ib = in + (size_t)b * 2048 * 1024;
    ushort_t* ob = out + (size_t)b * 1024 * 2048;
    int r0 = blockIdx.y * 64, c0 = blockIdx.x * 64;  // r over n, c over (h*64+d)
    int t = threadIdx.x, r = t >> 2, j = (t & 3) * 16;
    const ushort_t* ip = ib + (size_t)(r0 + r) * 1024 + c0 + j;
    *(short8*)(&Ls[r][j])     = *(const short8*)(ip);
    *(short8*)(&Ls[r][j + 8]) = *(const short8*)(ip + 8);
    __syncthreads();
    __align__(16) ushort_t tmp[16];
    #pragma unroll
    for (int i = 0; i < 16; ++i) tmp[i] = Ls[j + i][r];
    ushort_t* op = ob + (size_t)(c0 + r) * 2048 + r0 + j;
    *(short8*)(op)     = *(short8*)(tmp);
    *(short8*)(op + 8) = *(short8*)(tmp + 8);
}

// ---------------------------------------------------------------------------
// bf16 MFMA GEMM: C[M,N] = A[M,K] @ Bt[N,K]^T + bias.
// BM x 128 tile, BK=64, 256 threads (4 waves, 2x2), 16x16x32 MFMA.
// global_load_lds staging with XOR chunk swizzle. z-grid selects weight/bias
// (fused QKV).
// ---------------------------------------------------------------------------
template<int BM, bool OUT_BF16>
__global__ __launch_bounds__(256) void gemm_mfma(
    const ushort_t* __restrict__ A, const ushort_t* __restrict__ Bt0,
    const float* __restrict__ b0, const float* __restrict__ b1,
    const float* __restrict__ b2, void* __restrict__ out0,
    int M, int N, int K)
{
    constexpr int BK = 64;
    constexpr int MI = BM / 32;          // m-tiles of 16 per wave
    __shared__ ushort_t As[BM * BK];
    __shared__ ushort_t Bs[128 * BK];

    int z = blockIdx.z;
    const ushort_t* Bt = Bt0 + (size_t)z * N * K;
    const float* bias = (z == 0) ? b0 : (z == 1) ? b1 : b2;

    int t = threadIdx.x;
    int lane = t & 63, wv = t >> 6;
    int wr = wv >> 1, wc = wv & 1;
    int quad = lane >> 4, ln16 = lane & 15;

    int row0 = blockIdx.y * BM;
    int col0 = blockIdx.x * 128;

    const f32x4 zero4 = {0.f, 0.f, 0.f, 0.f};
    f32x4 acc[MI][4];
    #pragma unroll
    for (int i = 0; i < MI; ++i)
        #pragma unroll
        for (int j = 0; j < 4; ++j) acc[i][j] = zero4;

    for (int kt = 0; kt < K; kt += BK) {
        #pragma unroll
        for (int c = 0; c < BM / 32; ++c) {
            int idx = c * 256 + t;
            int r = idx >> 3, ch = idx & 7;
            int g = ch ^ (r & 7);
            gld16(A + (size_t)(row0 + r) * K + kt + g * 8,
                  As + (size_t)(c * 256 + wv * 64) * 8);
        }
        #pragma unroll
        for (int c = 0; c < 4; ++c) {
            int idx = c * 256 + t;
            int r = idx >> 3, ch = idx & 7;
            int g = ch ^ (r & 7);
            gld16(Bt + (size_t)(col0 + r) * K + kt + g * 8,
                  Bs + (size_t)(c * 256 + wv * 64) * 8);
        }
        __syncthreads();
        #pragma unroll
        for (int s = 0; s < 2; ++s) {
            bf16x8 af[MI], bf[4];
            int g = s * 4 + quad;
            #pragma unroll
            for (int i = 0; i < MI; ++i) {
                int m = wr * (BM / 2) + i * 16 + ln16;
                af[i] = *(const bf16x8*)(As + (size_t)(m * 8 + (g ^ (m & 7))) * 8);
            }
            #pragma unroll
            for (int j = 0; j < 4; ++j) {
                int n = wc * 64 + j * 16 + ln16;
                bf[j] = *(const bf16x8*)(Bs + (size_t)(n * 8 + (g ^ (n & 7))) * 8);
            }
            #pragma unroll
            for (int i = 0; i < MI; ++i)
                #pragma unroll
                for (int j = 0; j < 4; ++j)
                    acc[i][j] = __builtin_amdgcn_mfma_f32_16x16x32_bf16(
                        af[i], bf[j], acc[i][j], 0, 0, 0);
        }
        __syncthreads();
    }

    #pragma unroll
    for (int j = 0; j < 4; ++j) {
        int col = col0 + wc * 64 + j * 16 + ln16;
        float bv = bias[col];
        #pragma unroll
        for (int i = 0; i < MI; ++i) {
            int rowb = row0 + wr * (BM / 2) + i * 16 + quad * 4;
            #pragma unroll
            for (int r = 0; r < 4; ++r) {
                float val = acc[i][j][r] + bv;
                if (OUT_BF16) {
                    ushort_t* out = (ushort_t*)out0 + (size_t)z * M * N;
                    out[(size_t)(rowb + r) * N + col] = f2bf(val);
                } else {
                    float* out = (float*)out0;
                    out[(size_t)(rowb + r) * N + col] = val;
                }
            }
        }
    }
}

// ---------------------------------------------------------------------------
// MFMA flash attention, S^T formulation, register-resident P.
// Block = 256 thr (4 waves x 16 Q rows), 64 Q rows per block, one (b,h).
// Key tiles of 128. S^T = mfma_16x16x32(K_frag, Q_frag): lane owns q-row ln16.
// KEY TRICK: the S^T C-layout (k=quad*4+r, n=ln16) is exactly the B-operand
// layout of v_mfma_f32_16x16x16_bf16, so PV = mfma16(V^T_Afrag, P_regs) with
// NO LDS round-trip for P. O accumulates transposed (O^T[d][qrow=ln16]), so
// alpha/l are in-lane. q is pre-scaled by inner^-0.5 * log2(e); softmax in
// base 2 (identical weights). Epilogue fuses SiLU -> bf16 packed stores.
// ---------------------------------------------------------------------------
__global__ __launch_bounds__(256, 4) void flash_mfma(
    const ushort_t* __restrict__ qb, const ushort_t* __restrict__ kb,
    const ushort_t* __restrict__ vT, ushort_t* __restrict__ ob)
{
    const int N = 2048, HD = 1024, D = 64, H = 16;
    const int KT = 128;
    __shared__ ushort_t Ks[128 * 64];      // [key][d], 8-chunk xor swizzle
    __shared__ ushort_t Vs[64 * 128];      // [d][key], 16-chunk xor swizzle

    int t = threadIdx.x, lane = t & 63, wv = t >> 6;
    int quad = lane >> 4, ln16 = lane & 15;
    int qt = blockIdx.x, h = blockIdx.y, b = blockIdx.z;

    size_t qk_base = (size_t)b * N * HD + (size_t)h * D;
    size_t vt_base = (size_t)(b * H + h) * D * N;

    // Q fragment (B-operand, K=32) for this wave's 16 rows.
    bf16x8 qf[2];
    {
        const ushort_t* qp = qb + qk_base + (size_t)(qt * 64 + wv * 16 + ln16) * HD;
        qf[0] = *(const bf16x8*)(qp + quad * 8);
        qf[1] = *(const bf16x8*)(qp + 32 + quad * 8);
    }

    const f32x4 zero4 = {0.f, 0.f, 0.f, 0.f};
    f32x4 oacc[4];                         // O^T[d = mt*16+quad*4+r][qrow=ln16]
    #pragma unroll
    for (int j = 0; j < 4; ++j) oacc[j] = zero4;
    float mcur = -INFINITY, lcur = 0.f;    // softmax state for q-row ln16

    for (int kt = 0; kt < N; kt += KT) {
        __syncthreads();   // all waves done with previous Ks/Vs
        #pragma unroll
        for (int c = 0; c < 4; ++c) {
            int idx = c * 256 + t;
            int r = idx >> 3, ch = idx & 7, g = ch ^ (r & 7);
            gld16(kb + qk_base + (size_t)(kt + r) * HD + g * 8,
                  Ks + (size_t)(c * 256 + wv * 64) * 8);
        }
        #pragma unroll
        for (int c = 0; c < 4; ++c) {
            int idx = c * 256 + t;
            int r = idx >> 4, ch = idx & 15, g = ch ^ (r & 15);
            gld16(vT + vt_base + (size_t)r * N + kt + g * 8,
                  Vs + (size_t)(c * 256 + wv * 64) * 8);
        }
        __syncthreads();

        // S^T = K @ Q^T : C-layout row=key(tile*16+quad*4+r), col=qrow(ln16).
        f32x4 st[8];
        #pragma unroll
        for (int j = 0; j < 8; ++j) st[j] = zero4;
        #pragma unroll
        for (int s = 0; s < 2; ++s) {
            int g = s * 4 + quad;
            #pragma unroll
            for (int j = 0; j < 8; ++j) {
                int n = j * 16 + ln16;
                bf16x8 kf = *(const bf16x8*)(Ks + ((size_t)n * 8 + (g ^ (n & 7))) * 8);
                st[j] = __builtin_amdgcn_mfma_f32_16x16x32_bf16(kf, qf[s], st[j], 0, 0, 0);
            }
        }

        // online softmax (base 2) for q-row ln16: 32 scores in-thread.
        float mx = st[0][0];
        #pragma unroll
        for (int j = 0; j < 8; ++j) {
            float a = fmaxf(fmaxf(st[j][0], st[j][1]), fmaxf(st[j][2], st[j][3]));
            mx = fmaxf(mx, a);
        }
        mx = fmaxf(mx, __shfl_xor(mx, 16, 64));
        mx = fmaxf(mx, __shfl_xor(mx, 32, 64));
        float mnew = fmaxf(mcur, mx);
        float alpha = exp2f(mcur - mnew);
        mcur = mnew;

        float psum = 0.f;
        #pragma unroll
        for (int j = 0; j < 8; ++j) {
            st[j][0] = exp2f(st[j][0] - mnew);
            st[j][1] = exp2f(st[j][1] - mnew);
            st[j][2] = exp2f(st[j][2] - mnew);
            st[j][3] = exp2f(st[j][3] - mnew);
            psum += (st[j][0] + st[j][1]) + (st[j][2] + st[j][3]);
        }
        psum += __shfl_xor(psum, 16, 64);
        psum += __shfl_xor(psum, 32, 64);
        lcur = lcur * alpha + psum;

        #pragma unroll
        for (int j = 0; j < 4; ++j) oacc[j] *= alpha;   // in-lane rescale

        // O^T += V^T @ P : A = V^T frag (K=16), B = P straight from st regs.
        #pragma unroll
        for (int tile = 0; tile < 8; ++tile) {
            uint2 uu;
            uu.x = pk2(st[tile][0], st[tile][1]);
            uu.y = pk2(st[tile][2], st[tile][3]);
            bf16x4 pf = __builtin_bit_cast(bf16x4, uu);
            int ch = 2 * tile + (quad >> 1);
            #pragma unroll
            for (int mt = 0; mt < 4; ++mt) {
                int dd = mt * 16 + ln16;
                int sw = ch ^ (dd & 15);
                bf16x4 vf = *(const bf16x4*)(Vs + (size_t)dd * 128 + sw * 8 + (quad & 1) * 4);
                oacc[mt] = mfma16(vf, pf, oacc[mt]);
            }
        }
    }

    // epilogue: O^T/l, SiLU, packed bf16 stores. Lane ln16 owns q-row ln16.
    float inv = 1.0f / lcur;
    size_t rowoff = qk_base + (size_t)(qt * 64 + wv * 16 + ln16) * HD;
    #pragma unroll
    for (int mt = 0; mt < 4; ++mt) {
        float o0 = silu_f(oacc[mt][0] * inv);
        float o1 = silu_f(oacc[mt][1] * inv);
        float o2 = silu_f(oacc[mt][2] * inv);
        float o3 = silu_f(oacc[mt][3] * inv);
        uint2 uu;
        uu.x = pk2(o0, o1);
        uu.y = pk2(o2, o3);
        *(uint2*)(ob + rowoff + mt * 16 + quad * 4) = uu;
    }
}

// ---------------------------------------------------------------------------
extern "C" void kernel_launch(void* const* d_in, const int* in_sizes, int n_in,
                              void* d_out, int out_size, void* d_ws, size_t ws_size,
                              hipStream_t stream) {
    const float* x    = (const float*)d_in[0];
    const float* w_q  = (const float*)d_in[1];
    const float* b_q  = (const float*)d_in[2];
    const float* w_k  = (const float*)d_in[3];
    const float* b_k  = (const float*)d_in[4];
    const float* w_v  = (const float*)d_in[5];
    const float* b_v  = (const float*)d_in[6];
    const float* g_q  = (const float*)d_in[7];
    const float* be_q = (const float*)d_in[8];
    const float* g_k  = (const float*)d_in[9];
    const float* be_k = (const float*)d_in[10];
    const float* w_o  = (const float*)d_in[11];
    const float* b_o  = (const float*)d_in[12];
    float* out = (float*)d_out;

    const int B = 2, N = 2048, C = 1024, H = 16, INNER = 1024;
    const int M = B * N;                       // 4096
    const size_t MC = (size_t)M * C;           // 4194304

    // ws layout (ushort elems): sx | qkv(3x) | vT | wT(4x)   = 48 MB
    ushort_t* ws  = (ushort_t*)d_ws;
    ushort_t* sx  = ws;                        // [M][1024] bf16 (later reused as o)
    ushort_t* qkv = ws + MC;                   // [3][M][1024]
    ushort_t* vTp = ws + 4 * MC;               // [B][1024][2048]
    ushort_t* wT  = ws + 5 * MC;               // [4][1024][1024]

    ushort_t* qbuf = qkv;
    ushort_t* kbuf = qkv + MC;
    ushort_t* vbuf = qkv + 2 * MC;
    ushort_t* obuf = sx;                       // sx dead after QKV GEMM

    // 1. weight transposes fp32 [K][N] -> bf16 [N][K]
    W4 w4; w4.p[0] = w_q; w4.p[1] = w_k; w4.p[2] = w_v; w4.p[3] = w_o;
    transpose_w<<<dim3(16, 16, 4), 256, 0, stream>>>(w4, wT);

    // 2. pre-norm + SiLU -> bf16
    ln_silu_kernel<<<M, 256, 0, stream>>>(x, sx);

    // 3. fused QKV GEMM (bf16 out, bias)
    gemm_mfma<128, true><<<dim3(INNER / 128, M / 128, 3), 256, 0, stream>>>(
        sx, wT, b_q, b_k, b_v, qkv, M, INNER, C);

    // 4. q/k layernorms (bf16 in place); q scaled by inner^-0.5 * log2(e)
    //    (softmax computed in base 2 -> identical weights)
    ln_affine_bf16<<<M, 256, 0, stream>>>(qbuf, g_q, be_q, 0.03125f * 1.44269504f);
    ln_affine_bf16<<<M, 256, 0, stream>>>(kbuf, g_k, be_k, 1.0f);

    // 5. V^T: [b][n][h*64+d] -> [b][h*64+d][n]
    transpose_v<<<dim3(16, 32, 2), 256, 0, stream>>>(vbuf, vTp);

    // 6. flash attention (writes silu(o) bf16 into obuf)
    flash_mfma<<<dim3(N / 64, H, B), 256, 0, stream>>>(qbuf, kbuf, vTp, obuf);

    // 7. final GEMM -> fp32 out
    gemm_mfma<64, false><<<dim3(C / 128, M / 64, 1), 256, 0, stream>>>(
        obuf, wT + (size_t)3 * 1024 * 1024, b_o, b_o, b_o, out, M, C, INNER);
}